// Round 3
// baseline (341.257 us; speedup 1.0000x reference)
//
#include <hip/hip_runtime.h>
#include <math.h>

// Shapes (fixed by setup_inputs): x [B=4, C=64, D=32, H=64, W=64] f32
#define BB 4
#define CC 64
#define DD 32
#define HH 64
#define WW 64
#define DHW (DD * HH * WW)       // 131072 = 2^17
#define NP  (BB * DHW)           // 524288 spatial positions
#define CDHW (CC * DHW)          // 8388608 = 2^23
#define TOTAL (BB * CDHW)        // 33554432
//
// ZERO-WORKSPACE SCHEME (d_ws size is unknown -> don't touch it):
//   out plane c=1 of batch b  <- avg pool      (kernel 1)
//   out plane c=2 of batch b  <- max pool      (kernel 1)
//   out plane c=0 of batch b  <- att           (kernel 2, reads planes 1,2)
//   kernel 3: thread owns spatial float4 (b,s); reads att from plane 0
//   FIRST, then overwrites out[b,c,s] = x[b,c,s]*att for all c=0..63.
//   att[b,s] is read only by the thread that owns (b,s) -> no race.

// ---------------- Kernel 1: channel mean+max pooling -----------------
__global__ void pool_kernel(const float* __restrict__ x,
                            float* __restrict__ out) {
    int tid4 = blockIdx.x * blockDim.x + threadIdx.x;   // 0 .. NP/4-1
    int i = tid4 * 4;                                   // flat (b,s)
    int b = i >> 17;                                    // / DHW
    int s = i & (DHW - 1);
    const float* base = x + (size_t)b * CDHW + s;
    float4 v = *(const float4*)base;
    float4 sum = v, mx = v;
#pragma unroll 8
    for (int c = 1; c < CC; ++c) {
        float4 u = *(const float4*)(base + (size_t)c * DHW);
        sum.x += u.x; sum.y += u.y; sum.z += u.z; sum.w += u.w;
        mx.x = fmaxf(mx.x, u.x); mx.y = fmaxf(mx.y, u.y);
        mx.z = fmaxf(mx.z, u.z); mx.w = fmaxf(mx.w, u.w);
    }
    const float inv = 1.0f / (float)CC;
    float4 av; av.x = sum.x * inv; av.y = sum.y * inv;
    av.z = sum.z * inv; av.w = sum.w * inv;
    *(float4*)(out + (size_t)b * CDHW + 1 * DHW + s) = av;   // avg -> plane 1
    *(float4*)(out + (size_t)b * CDHW + 2 * DHW + s) = mx;   // max -> plane 2
}

// ---------------- Kernel 2: 7x7x7 conv (2ch) + sigmoid ---------------
// Block = 256 threads = 16 h-rows x 16 w-groups of 4 outputs. Weights in LDS.
__global__ void conv_kernel(const float* __restrict__ cw,
                            float* __restrict__ out) {
    __shared__ float wsm[2 * 343];
    for (int idx = threadIdx.x; idx < 686; idx += 256)
        wsm[idx] = cw[idx];
    __syncthreads();

    int bx = blockIdx.x;                 // B * D * (H/16) = 512 blocks
    int hblk = bx & 3;                   // H/16 = 4
    int d = (bx >> 2) & 31;              // D = 32
    int b = bx >> 7;
    int tid = threadIdx.x;
    int wg = tid & 15;
    int h = (hblk << 4) + (tid >> 4);
    int w0 = wg << 2;

    float acc0 = 0.f, acc1 = 0.f, acc2 = 0.f, acc3 = 0.f;

    for (int ch = 0; ch < 2; ++ch) {
        // avg pool lives in plane 1, max pool in plane 2
        const float* plane = out + (size_t)b * CDHW + (size_t)(ch + 1) * DHW;
        const float* wch = wsm + ch * 343;
#pragma unroll
        for (int kd = 0; kd < 7; ++kd) {
            int dd = d + kd - 3;
            if (dd < 0 || dd >= DD) continue;
#pragma unroll
            for (int kh = 0; kh < 7; ++kh) {
                int hh = h + kh - 3;
                if (hh < 0 || hh >= HH) continue;
                const float* row = plane + ((dd << 6) + hh) * WW;
                float vals[10];
#pragma unroll
                for (int t = 0; t < 10; ++t) {
                    int ww = w0 - 3 + t;
                    vals[t] = (ww >= 0 && ww < WW) ? row[ww] : 0.f;
                }
                const float* wrow = wch + (kd * 7 + kh) * 7;
#pragma unroll
                for (int kw = 0; kw < 7; ++kw) {
                    float wv = wrow[kw];
                    acc0 = fmaf(vals[kw + 0], wv, acc0);
                    acc1 = fmaf(vals[kw + 1], wv, acc1);
                    acc2 = fmaf(vals[kw + 2], wv, acc2);
                    acc3 = fmaf(vals[kw + 3], wv, acc3);
                }
            }
        }
    }

    // att -> plane 0
    size_t o = (size_t)b * CDHW + (size_t)((d << 6) + h) * WW + w0;
    out[o + 0] = 1.f / (1.f + __expf(-acc0));
    out[o + 1] = 1.f / (1.f + __expf(-acc1));
    out[o + 2] = 1.f / (1.f + __expf(-acc2));
    out[o + 3] = 1.f / (1.f + __expf(-acc3));
}

// ---------------- Kernel 3: out[b,c,s] = x[b,c,s] * att[b,s] ---------
// Thread owns one spatial float4 across ALL channels; reads att first.
__global__ void scale_kernel(const float* __restrict__ x,
                             float* __restrict__ out) {
    int tid4 = blockIdx.x * blockDim.x + threadIdx.x;   // 0 .. NP/4-1
    int i = tid4 * 4;
    int b = i >> 17;
    int s = i & (DHW - 1);
    size_t base = (size_t)b * CDHW + s;
    float4 av = *(const float4*)(out + base);            // att from plane 0
#pragma unroll 4
    for (int c = 0; c < CC; ++c) {
        float4 xv = *(const float4*)(x + base + (size_t)c * DHW);
        float4 o;
        o.x = xv.x * av.x; o.y = xv.y * av.y;
        o.z = xv.z * av.z; o.w = xv.w * av.w;
        *(float4*)(out + base + (size_t)c * DHW) = o;
    }
}

extern "C" void kernel_launch(void* const* d_in, const int* in_sizes, int n_in,
                              void* d_out, int out_size, void* d_ws, size_t ws_size,
                              hipStream_t stream) {
    const float* x  = (const float*)d_in[0];
    const float* cw = (const float*)d_in[1];
    float* out = (float*)d_out;

    pool_kernel<<<NP / 4 / 256, 256, 0, stream>>>(x, out);
    conv_kernel<<<BB * DD * (HH / 16), 256, 0, stream>>>(cw, out);
    scale_kernel<<<NP / 4 / 256, 256, 0, stream>>>(x, out);
}

// Round 4
// 291.710 us; speedup vs baseline: 1.1699x; 1.1699x over previous
//
#include <hip/hip_runtime.h>
#include <math.h>

// Shapes (fixed by setup_inputs): x [B=4, C=64, D=32, H=64, W=64] f32
#define BB 4
#define CC 64
#define DD 32
#define HH 64
#define WW 64
#define DHW (DD * HH * WW)       // 131072 = 2^17
#define NP  (BB * DHW)           // 524288 spatial positions
#define CDHW (CC * DHW)          // 8388608 = 2^23
//
// ZERO-WORKSPACE SCHEME (d_ws size unknown -> never touched):
//   out plane c=1 of batch b  <- avg pool      (kernel 1)
//   out plane c=2 of batch b  <- max pool      (kernel 1)
//   out plane c=0 of batch b  <- att           (kernel 2, reads planes 1,2)
//   kernel 3: thread owns spatial float4 (b,s); reads att from plane 0
//   FIRST, then overwrites out[b,c,s] = x[b,c,s]*att for all c.

// ---------------- Kernel 1: channel mean+max pooling -----------------
__global__ void pool_kernel(const float* __restrict__ x,
                            float* __restrict__ out) {
    int tid4 = blockIdx.x * blockDim.x + threadIdx.x;   // 0 .. NP/4-1
    int i = tid4 * 4;
    int b = i >> 17;
    int s = i & (DHW - 1);
    const float* base = x + (size_t)b * CDHW + s;
    float4 v = *(const float4*)base;
    float4 sum = v, mx = v;
#pragma unroll 8
    for (int c = 1; c < CC; ++c) {
        float4 u = *(const float4*)(base + (size_t)c * DHW);
        sum.x += u.x; sum.y += u.y; sum.z += u.z; sum.w += u.w;
        mx.x = fmaxf(mx.x, u.x); mx.y = fmaxf(mx.y, u.y);
        mx.z = fmaxf(mx.z, u.z); mx.w = fmaxf(mx.w, u.w);
    }
    const float inv = 1.0f / (float)CC;
    float4 av; av.x = sum.x * inv; av.y = sum.y * inv;
    av.z = sum.z * inv; av.w = sum.w * inv;
    *(float4*)(out + (size_t)b * CDHW + 1 * DHW + s) = av;   // avg -> plane 1
    *(float4*)(out + (size_t)b * CDHW + 2 * DHW + s) = mx;   // max -> plane 2
}

// ---------------- Kernel 2: 7x7x7 conv (2ch) + sigmoid ---------------
// Wave-private double-buffered LDS plane tiles; NO barriers.
// Block 256 thr = 4 waves; wave = 4 h-rows x 16 w-groups (4 outputs each).
// Grid: B*D*(H/16) = 512 blocks.
#define ROWF 76                 // 72 used floats + 4 pad
#define PLANEF (10 * ROWF)      // 760 floats per staged plane

__global__ __launch_bounds__(256) void conv_kernel(const float* __restrict__ cw,
                                                   float* __restrict__ out) {
    __shared__ float lds[4 * 2 * PLANEF];   // 4 waves x 2 bufs = 24.3 KB

    int bx = blockIdx.x;
    int hblk = bx & 3;                   // H/16
    int d = (bx >> 2) & 31;
    int b = bx >> 7;
    int tid = threadIdx.x;
    int wv = tid >> 6, lane = tid & 63;
    int wg = lane & 15, hl = lane >> 4;
    int h0w = (hblk << 4) + (wv << 2);   // wave's first output row
    int h = h0w + hl;
    int w0 = wg << 2;

    float* region = lds + wv * (2 * PLANEF);

    // Staging descriptors: 180 float4 chunks (10 rows x 18), 3 per lane.
    // Chunk k: r=k/18, c=k%18 -> LDS row r, float col c*4 (covers w=c*4-4..).
    int roff[3], goff[3]; bool okhc[3]; bool act[3];
#pragma unroll
    for (int j = 0; j < 3; ++j) {
        int k = lane + 64 * j;
        int r = k / 18, c = k - r * 18;
        int hh = h0w - 3 + r;
        act[j]  = (k < 180);
        okhc[j] = act[j] && (hh >= 0) && (hh < HH) && (c >= 1) && (c <= 16);
        roff[j] = r * ROWF + (c << 2);
        goff[j] = (hh << 6) + (c << 2) - 4;
    }

    const float* outb = out + (size_t)b * CDHW;
    float acc0 = 0.f, acc1 = 0.f, acc2 = 0.f, acc3 = 0.f;

    auto load_plane = [&](int p, float4* st) {
        int ch = (p >= 7) ? 1 : 0;
        int kd = p - ch * 7;
        int dd = d + kd - 3;
        bool dok = (dd >= 0) && (dd < DD);
        const float* pb = outb + (size_t)(ch + 1) * DHW + ((size_t)dd << 12);
#pragma unroll
        for (int j = 0; j < 3; ++j) {
            float4 v = make_float4(0.f, 0.f, 0.f, 0.f);
            if (dok && okhc[j]) v = *(const float4*)(pb + goff[j]);
            st[j] = v;
        }
    };
    auto write_plane = [&](float* buf, const float4* st) {
#pragma unroll
        for (int j = 0; j < 3; ++j)
            if (act[j]) *(float4*)(buf + roff[j]) = st[j];
    };
    auto compute_plane = [&](const float* buf, int p) {
        int ch = (p >= 7) ? 1 : 0;
        int kd = p - ch * 7;
        const float* wp = cw + ch * 343 + kd * 49;   // uniform -> s_load
#pragma unroll
        for (int kh = 0; kh < 7; ++kh) {
            const float* rp = buf + (hl + kh) * ROWF + w0;
            float4 q0 = *(const float4*)(rp);
            float4 q1 = *(const float4*)(rp + 4);
            float4 q2 = *(const float4*)(rp + 8);
            float a[12] = {q0.x, q0.y, q0.z, q0.w,
                           q1.x, q1.y, q1.z, q1.w,
                           q2.x, q2.y, q2.z, q2.w};
            const float* wr = wp + kh * 7;
#pragma unroll
            for (int kw = 0; kw < 7; ++kw) {
                float wvv = wr[kw];
                acc0 = fmaf(a[kw + 1], wvv, acc0);
                acc1 = fmaf(a[kw + 2], wvv, acc1);
                acc2 = fmaf(a[kw + 3], wvv, acc2);
                acc3 = fmaf(a[kw + 4], wvv, acc3);
            }
        }
    };

    float4 st[3];
    load_plane(0, st);
    write_plane(region, st);
    for (int p = 0; p < 14; ++p) {
        float* cur = region + (p & 1) * PLANEF;
        float* nxt = region + ((p + 1) & 1) * PLANEF;
        float4 nx[3];
        if (p < 13) load_plane(p + 1, nx);     // overlaps compute below
        compute_plane(cur, p);
        if (p < 13) write_plane(nxt, nx);
    }

    size_t o = (size_t)b * CDHW + (size_t)((d << 6) + h) * WW + w0;
    float4 r;
    r.x = 1.f / (1.f + __expf(-acc0));
    r.y = 1.f / (1.f + __expf(-acc1));
    r.z = 1.f / (1.f + __expf(-acc2));
    r.w = 1.f / (1.f + __expf(-acc3));
    *(float4*)(out + o) = r;                   // att -> plane 0
}

// ---------------- Kernel 3: out[b,c,s] = x[b,c,s] * att[b,s] ---------
__global__ void scale_kernel(const float* __restrict__ x,
                             float* __restrict__ out) {
    int tid4 = blockIdx.x * blockDim.x + threadIdx.x;   // 0 .. NP/4-1
    int i = tid4 * 4;
    int b = i >> 17;
    int s = i & (DHW - 1);
    size_t base = (size_t)b * CDHW + s;
    float4 av = *(const float4*)(out + base);            // att from plane 0
#pragma unroll 4
    for (int c = 0; c < CC; ++c) {
        float4 xv = *(const float4*)(x + base + (size_t)c * DHW);
        float4 o;
        o.x = xv.x * av.x; o.y = xv.y * av.y;
        o.z = xv.z * av.z; o.w = xv.w * av.w;
        *(float4*)(out + base + (size_t)c * DHW) = o;
    }
}

extern "C" void kernel_launch(void* const* d_in, const int* in_sizes, int n_in,
                              void* d_out, int out_size, void* d_ws, size_t ws_size,
                              hipStream_t stream) {
    const float* x  = (const float*)d_in[0];
    const float* cw = (const float*)d_in[1];
    float* out = (float*)d_out;

    pool_kernel<<<NP / 4 / 256, 256, 0, stream>>>(x, out);
    conv_kernel<<<BB * DD * (HH / 16), 256, 0, stream>>>(cw, out);
    scale_kernel<<<NP / 4 / 256, 256, 0, stream>>>(x, out);
}

// Round 5
// 276.687 us; speedup vs baseline: 1.2334x; 1.0543x over previous
//
#include <hip/hip_runtime.h>
#include <math.h>

// Shapes (fixed by setup_inputs): x [B=4, C=64, D=32, H=64, W=64] f32
#define BB 4
#define CC 64
#define DD 32
#define HH 64
#define WW 64
#define DHW (DD * HH * WW)       // 131072 = 2^17
#define NP  (BB * DHW)           // 524288 spatial positions
#define CDHW (CC * DHW)          // 8388608 = 2^23

#define ROWF 76                  // 72 used floats + 4 pad
#define PLANEF (10 * ROWF)       // staged plane floats per wave

// ---------------- Kernel 1: channel mean+max pooling -----------------
// avgp/maxp are plane bases with per-batch stride `bstride`:
//   ws path:       avgp=ws,        maxp=ws+NP,       bstride=DHW
//   fallback path: avgp=out+DHW,   maxp=out+2*DHW,   bstride=CDHW
__global__ void pool_kernel(const float* __restrict__ x,
                            float* __restrict__ avgp,
                            float* __restrict__ maxp,
                            size_t bstride) {
    int tid4 = blockIdx.x * blockDim.x + threadIdx.x;   // 0 .. NP/4-1
    int i = tid4 * 4;
    int b = i >> 17;
    int s = i & (DHW - 1);
    const float* base = x + (size_t)b * CDHW + s;
    float4 v = *(const float4*)base;
    float4 sum = v, mx = v;
#pragma unroll 8
    for (int c = 1; c < CC; ++c) {
        float4 u = *(const float4*)(base + (size_t)c * DHW);
        sum.x += u.x; sum.y += u.y; sum.z += u.z; sum.w += u.w;
        mx.x = fmaxf(mx.x, u.x); mx.y = fmaxf(mx.y, u.y);
        mx.z = fmaxf(mx.z, u.z); mx.w = fmaxf(mx.w, u.w);
    }
    const float inv = 1.0f / (float)CC;
    float4 av; av.x = sum.x * inv; av.y = sum.y * inv;
    av.z = sum.z * inv; av.w = sum.w * inv;
    *(float4*)(avgp + (size_t)b * bstride + s) = av;
    *(float4*)(maxp + (size_t)b * bstride + s) = mx;
}

// ---------------- conv core: wave-private dbuf LDS, no barriers ------
// Returns sigmoid(conv) for this thread's 4 outputs (h = h0w + lane>>4,
// w = 4*(lane&15) .. +3).
__device__ __forceinline__ float4 conv_sigmoid(const float* __restrict__ avgp,
                                               const float* __restrict__ maxp,
                                               size_t bstride,
                                               const float* __restrict__ cw,
                                               float* region,
                                               int b, int d, int h0w, int lane) {
    int wg = lane & 15, hl = lane >> 4;
    int w0 = wg << 2;

    // Staging: 180 float4 chunks (10 rows x 18 cols), 3 per lane.
    int roff[3], goff[3]; bool okhc[3]; bool act[3];
#pragma unroll
    for (int j = 0; j < 3; ++j) {
        int k = lane + 64 * j;
        int r = k / 18, c = k - r * 18;
        int hh = h0w - 3 + r;
        act[j]  = (k < 180);
        okhc[j] = act[j] && (hh >= 0) && (hh < HH) && (c >= 1) && (c <= 16);
        roff[j] = r * ROWF + (c << 2);
        goff[j] = (hh << 6) + (c << 2) - 4;
    }

    float acc0 = 0.f, acc1 = 0.f, acc2 = 0.f, acc3 = 0.f;

    auto load_plane = [&](int p, float4* st) {
        int ch = (p >= 7) ? 1 : 0;
        int kd = p - ch * 7;
        int dd = d + kd - 3;
        bool dok = (dd >= 0) && (dd < DD);
        const float* pb = (ch == 0 ? avgp : maxp) + (size_t)b * bstride
                        + ((size_t)dd << 12);
#pragma unroll
        for (int j = 0; j < 3; ++j) {
            float4 v = make_float4(0.f, 0.f, 0.f, 0.f);
            if (dok && okhc[j]) v = *(const float4*)(pb + goff[j]);
            st[j] = v;
        }
    };
    auto write_plane = [&](float* buf, const float4* st) {
#pragma unroll
        for (int j = 0; j < 3; ++j)
            if (act[j]) *(float4*)(buf + roff[j]) = st[j];
    };
    auto compute_plane = [&](const float* buf, int p) {
        int ch = (p >= 7) ? 1 : 0;
        int kd = p - ch * 7;
        const float* wp = cw + ch * 343 + kd * 49;   // uniform -> scalar loads
#pragma unroll
        for (int kh = 0; kh < 7; ++kh) {
            const float* rp = buf + (hl + kh) * ROWF + w0;
            float4 q0 = *(const float4*)(rp);
            float4 q1 = *(const float4*)(rp + 4);
            float4 q2 = *(const float4*)(rp + 8);
            float a[12] = {q0.x, q0.y, q0.z, q0.w,
                           q1.x, q1.y, q1.z, q1.w,
                           q2.x, q2.y, q2.z, q2.w};
            const float* wr = wp + kh * 7;
#pragma unroll
            for (int kw = 0; kw < 7; ++kw) {
                float wvv = wr[kw];
                acc0 = fmaf(a[kw + 1], wvv, acc0);
                acc1 = fmaf(a[kw + 2], wvv, acc1);
                acc2 = fmaf(a[kw + 3], wvv, acc2);
                acc3 = fmaf(a[kw + 4], wvv, acc3);
            }
        }
    };

    float4 st[3];
    load_plane(0, st);
    write_plane(region, st);
    for (int p = 0; p < 14; ++p) {
        float* cur = region + (p & 1) * PLANEF;
        float* nxt = region + ((p + 1) & 1) * PLANEF;
        float4 nx[3];
        if (p < 13) load_plane(p + 1, nx);     // overlaps compute below
        compute_plane(cur, p);
        if (p < 13) write_plane(nxt, nx);
    }

    float4 r;
    r.x = 1.f / (1.f + __expf(-acc0));
    r.y = 1.f / (1.f + __expf(-acc1));
    r.z = 1.f / (1.f + __expf(-acc2));
    r.w = 1.f / (1.f + __expf(-acc3));
    return r;
}

// -------- Fused conv+scale (ws path): att in regs, stream 64 ch ------
__global__ __launch_bounds__(256) void conv_scale_kernel(
        const float* __restrict__ x,
        const float* __restrict__ avgp,
        const float* __restrict__ maxp,
        const float* __restrict__ cw,
        float* __restrict__ out) {
    __shared__ float lds[4 * 2 * PLANEF];
    int bx = blockIdx.x;                 // 512
    int hblk = bx & 3;
    int d = (bx >> 2) & 31;
    int b = bx >> 7;
    int tid = threadIdx.x;
    int wv = tid >> 6, lane = tid & 63;
    int h0w = (hblk << 4) + (wv << 2);

    float4 att = conv_sigmoid(avgp, maxp, DHW, cw,
                              lds + wv * (2 * PLANEF), b, d, h0w, lane);

    int hl = lane >> 4, w0 = (lane & 15) << 2;
    int h = h0w + hl;
    size_t base = (size_t)b * CDHW + (size_t)((d << 6) + h) * WW + w0;
#pragma unroll 8
    for (int c = 0; c < CC; ++c) {
        float4 xv = *(const float4*)(x + base + (size_t)c * DHW);
        float4 o;
        o.x = xv.x * att.x; o.y = xv.y * att.y;
        o.z = xv.z * att.z; o.w = xv.w * att.w;
        *(float4*)(out + base + (size_t)c * DHW) = o;
    }
}

// -------- Fallback path (no ws): conv -> out plane 0, then scale -----
__global__ __launch_bounds__(256) void conv_kernel(const float* __restrict__ cw,
                                                   float* __restrict__ out) {
    __shared__ float lds[4 * 2 * PLANEF];
    int bx = blockIdx.x;
    int hblk = bx & 3;
    int d = (bx >> 2) & 31;
    int b = bx >> 7;
    int tid = threadIdx.x;
    int wv = tid >> 6, lane = tid & 63;
    int h0w = (hblk << 4) + (wv << 2);

    float4 att = conv_sigmoid(out + DHW, out + 2 * DHW, CDHW, cw,
                              lds + wv * (2 * PLANEF), b, d, h0w, lane);

    int hl = lane >> 4, w0 = (lane & 15) << 2;
    int h = h0w + hl;
    size_t o = (size_t)b * CDHW + (size_t)((d << 6) + h) * WW + w0;
    *(float4*)(out + o) = att;               // att -> plane 0
}

__global__ void scale_kernel(const float* __restrict__ x,
                             float* __restrict__ out) {
    int tid4 = blockIdx.x * blockDim.x + threadIdx.x;   // 0 .. NP/4-1
    int i = tid4 * 4;
    int b = i >> 17;
    int s = i & (DHW - 1);
    size_t base = (size_t)b * CDHW + s;
    float4 av = *(const float4*)(out + base);            // att from plane 0
#pragma unroll 8
    for (int c = 0; c < CC; ++c) {
        float4 xv = *(const float4*)(x + base + (size_t)c * DHW);
        float4 o;
        o.x = xv.x * av.x; o.y = xv.y * av.y;
        o.z = xv.z * av.z; o.w = xv.w * av.w;
        *(float4*)(out + base + (size_t)c * DHW) = o;
    }
}

extern "C" void kernel_launch(void* const* d_in, const int* in_sizes, int n_in,
                              void* d_out, int out_size, void* d_ws, size_t ws_size,
                              hipStream_t stream) {
    const float* x  = (const float*)d_in[0];
    const float* cw = (const float*)d_in[1];
    float* out = (float*)d_out;

    // Host-side branch on ws_size is deterministic per harness -> graph-safe.
    if (ws_size >= (size_t)2 * NP * sizeof(float)) {
        float* avgp = (float*)d_ws;
        float* maxp = avgp + NP;
        pool_kernel<<<NP / 4 / 256, 256, 0, stream>>>(x, avgp, maxp, DHW);
        conv_scale_kernel<<<BB * DD * (HH / 16), 256, 0, stream>>>(
            x, avgp, maxp, cw, out);
    } else {
        pool_kernel<<<NP / 4 / 256, 256, 0, stream>>>(x, out + DHW,
                                                      out + 2 * DHW, CDHW);
        conv_kernel<<<BB * DD * (HH / 16), 256, 0, stream>>>(cw, out);
        scale_kernel<<<NP / 4 / 256, 256, 0, stream>>>(x, out);
    }
}